// Round 5
// baseline (523.280 us; speedup 1.0000x reference)
//
#include <hip/hip_runtime.h>
#include <hip/hip_bf16.h>
#include <math.h>

// Problem constants (B=2,S=2048,D=1024,E=8,F=4096, capacity_factor=2.0)
#define T_TOK 4096
#define DDIM 1024
#define EXP 8
#define FDIM 4096
#define CAP 1024   // int(2.0 * 4096 / 8)

typedef __attribute__((ext_vector_type(8))) short short8;
typedef __attribute__((ext_vector_type(4))) float float4v;
typedef unsigned int u32;
typedef unsigned long long u64;

// ---- workspace layout (bytes) ----
#define O_EIDX   0            // int[4096]
#define O_GATE   (16<<10)     // float[4096]
#define O_COUNTS (32<<10)     // int[8]
#define O_SUMP   ((32<<10)+64)  // float[8]
#define O_ZSUM   ((32<<10)+128) // float[1]
#define O_TLIST  (40<<10)     // int[8*1024]
#define O_GSLOT  (72<<10)     // float[8*1024]
#define O_XB     (1<<20)      // bf16[8*1024*1024]   16 MiB
#define O_WT     (17<<20)     // bf16[8*4096*1024]   64 MiB (reused W1t then W2t)
#define O_H      (81<<20)     // bf16[8*1024*4096]   64 MiB
#define O_PT     (145<<20)    // bf16[nsplit][8*1024][1024] 32/64 MiB split-K partials
#define WS_NEED4 ((size_t)(145+64)<<20)

__device__ __forceinline__ unsigned short f2bf(float f) {
  __hip_bfloat16 b = __float2bfloat16(f);
  return *reinterpret_cast<unsigned short*>(&b);
}
__device__ __forceinline__ float bf2f(unsigned short u) {
  u32 x = ((u32)u) << 16;
  union { u32 u; float f; } c; c.u = x; return c.f;
}

__device__ __forceinline__ void gld16(const void* g, void* l) {
  __builtin_amdgcn_global_load_lds((const __attribute__((address_space(1))) u32*)g,
                                   (__attribute__((address_space(3))) u32*)l, 16, 0, 0);
}

// ---------------- router: logits (fp64 acc), softmax, argmax, loss partials ----------------
__global__ __launch_bounds__(256) void router_kernel(
    const float* __restrict__ x, const float* __restrict__ wg,
    int* __restrict__ eidx, float* __restrict__ gate,
    float* __restrict__ sum_probs, float* __restrict__ zsum)
{
  __shared__ float bp[9];
  const int tid = threadIdx.x;
  if (tid < 9) bp[tid] = 0.0f;
  __syncthreads();
  const int wv = tid >> 6, lane = tid & 63;
  const int t = blockIdx.x * 4 + wv;
  const float* xr = x + (size_t)t * DDIM;
  double acc[8] = {0,0,0,0,0,0,0,0};
#pragma unroll
  for (int j = 0; j < 4; j++) {
    const int d0 = j * 256 + lane * 4;
    const float4 xv = *(const float4*)&xr[d0];
    const float xd[4] = {xv.x, xv.y, xv.z, xv.w};
#pragma unroll
    for (int u = 0; u < 4; u++) {
      const float* wr = wg + (size_t)(d0 + u) * 8;
      const float4 w0 = *(const float4*)wr;
      const float4 w1 = *(const float4*)(wr + 4);
      const double xdd = (double)xd[u];
      acc[0] += xdd * (double)w0.x; acc[1] += xdd * (double)w0.y;
      acc[2] += xdd * (double)w0.z; acc[3] += xdd * (double)w0.w;
      acc[4] += xdd * (double)w1.x; acc[5] += xdd * (double)w1.y;
      acc[6] += xdd * (double)w1.z; acc[7] += xdd * (double)w1.w;
    }
  }
#pragma unroll
  for (int e = 0; e < 8; e++)
#pragma unroll
    for (int off = 32; off; off >>= 1)
      acc[e] += __shfl_xor(acc[e], off);
  if (lane == 0) {
    double m = acc[0]; int am = 0;
#pragma unroll
    for (int e = 1; e < 8; e++) if (acc[e] > m) { m = acc[e]; am = e; }
    float p[8]; float se = 0.f;
#pragma unroll
    for (int e = 0; e < 8; e++) { p[e] = __expf((float)(acc[e] - m)); se += p[e]; }
    const float inv = 1.f / se;
#pragma unroll
    for (int e = 0; e < 8; e++) atomicAdd(&bp[e], p[e] * inv);
    const float z = logf(se) + (float)m;
    atomicAdd(&bp[8], z * z);
    eidx[t] = am;
    gate[t] = p[am] * inv;
  }
  __syncthreads();
  if (tid < 8) atomicAdd(&sum_probs[tid], bp[tid]);
  if (tid == 8) atomicAdd(zsum, bp[8]);
}

// ---------------- scan: deterministic per-expert positions (token order) ----------------
__global__ __launch_bounds__(512) void scan_kernel(
    const int* __restrict__ eidx, const float* __restrict__ gate,
    int* __restrict__ tlist, float* __restrict__ gslot, int* __restrict__ counts)
{
  __shared__ int se[T_TOK];
  const int tid = threadIdx.x;
  for (int i = tid; i < T_TOK; i += 512) se[i] = eidx[i];
  __syncthreads();
  const int w = tid >> 6, lane = tid & 63;
  int base = 0;
  for (int ch = 0; ch < T_TOK / 64; ch++) {
    const int t = ch * 64 + lane;
    const int e = se[t];
    const u64 m = __ballot(e == w);
    if (e == w) {
      const int p = base + __popcll(m & ((1ull << lane) - 1ull));
      if (p < CAP) {
        tlist[w * CAP + p] = t;
        gslot[w * CAP + p] = gate[t];
      }
    }
    base += __popcll(m);
  }
  if (lane == 0) counts[w] = base;   // raw count (aux loss); cap applied at use
}

// ---------------- dispatch: gather kept tokens into compact bf16 buffer ----------------
__global__ __launch_bounds__(256) void dispatch_kernel(
    const float* __restrict__ x, const int* __restrict__ tlist,
    const int* __restrict__ counts, unsigned short* __restrict__ xb)
{
  const int wv = threadIdx.x >> 6, lane = threadIdx.x & 63;
  const int s = blockIdx.x * 4 + wv;           // slot id
  const int e = s >> 10, c = s & (CAP - 1);
  int cnt = counts[e]; cnt = cnt < CAP ? cnt : CAP;
  if (c >= cnt) return;
  const int t = tlist[s];
  const float* xr = x + (size_t)t * DDIM;
  unsigned short* orow = xb + (size_t)s * DDIM;
#pragma unroll
  for (int j = 0; j < 4; j++) {
    const int d0 = j * 256 + lane * 4;
    const float4 v = *(const float4*)&xr[d0];
    const u64 pk = (u64)f2bf(v.x) | ((u64)f2bf(v.y) << 16) |
                   ((u64)f2bf(v.z) << 32) | ((u64)f2bf(v.w) << 48);
    *(u64*)&orow[d0] = pk;
  }
}

// ---------------- transpose + fp32->bf16: [R][C] -> [C][R] per matrix ----------------
__global__ __launch_bounds__(256) void transpose_cvt(
    const float* __restrict__ src, unsigned short* __restrict__ dst, int R, int C)
{
  __shared__ float tile[64][65];
  const size_t mb = (size_t)blockIdx.z * (size_t)R * (size_t)C;
  const int r0 = blockIdx.y * 64, c0 = blockIdx.x * 64;
  const int t = threadIdx.x;
  const int lr = t >> 4, lc = (t & 15) * 4;
#pragma unroll
  for (int p = 0; p < 4; p++) {
    const float4 v = *(const float4*)&src[mb + (size_t)(r0 + p * 16 + lr) * C + c0 + lc];
    tile[p * 16 + lr][lc + 0] = v.x; tile[p * 16 + lr][lc + 1] = v.y;
    tile[p * 16 + lr][lc + 2] = v.z; tile[p * 16 + lr][lc + 3] = v.w;
  }
  __syncthreads();
  const int n = t >> 2;            // out row within tile (0..63)
  const int k0 = (t & 3) * 16;
  unsigned short o[16];
#pragma unroll
  for (int j = 0; j < 16; j++) o[j] = f2bf(tile[k0 + j][n]);
  unsigned short* d = &dst[mb + (size_t)(c0 + n) * R + r0 + k0];
  *(short8*)d = *(short8*)&o[0];
  *(short8*)(d + 8) = *(short8*)&o[8];
}

// ======================= GEMMs: M=32, N=256, BK=64, XOR-swizzled LDS =======================
// LDS store: chunk c (8 ushorts) of row r holds global k-chunk c ^ (r&7).
// Staging source offset per lane: ((lane&7) ^ (lane>>3)) * 8.
// Fragment read chunk: (ks*4 + quad) ^ (l15&7).
// 4 waves; wave w owns m[0,32) x n[w*64,(w+1)*64): acc[2][4]; 16 MFMA per barrier-pair.

// ---------------- GEMM1: h = relu(xb @ W1 + b1), bf16 out, 32x256 tile ----------------
__global__ __launch_bounds__(256) void gemm_ffn1(
    const unsigned short* __restrict__ xb, const unsigned short* __restrict__ w1t,
    const float* __restrict__ b1, unsigned short* __restrict__ h,
    const int* __restrict__ counts)
{
  __shared__ __align__(16) unsigned short As[32 * 64];
  __shared__ __align__(16) unsigned short Bs[256 * 64];
  const int e = blockIdx.z;
  int cnt = counts[e]; cnt = cnt < CAP ? cnt : CAP;
  const int m0 = blockIdx.y * 32;
  if (m0 >= cnt) return;
  const int n0 = blockIdx.x * 256;
  const int K = DDIM;
  const unsigned short* Ab = xb + ((size_t)e * CAP + m0) * K;
  const unsigned short* Bb = w1t + ((size_t)e * FDIM + n0) * K;

  const int tid = threadIdx.x;
  const int w = tid >> 6, lane = tid & 63;
  const int lrow = lane >> 3;
  const int lk_sw = ((lane & 7) ^ lrow) * 8;      // swizzled source k-offset
  const int l15 = lane & 15, quad = lane >> 4;
  const int xq = l15 & 7;
  const int co0 = ((0 * 4 + quad) ^ xq) * 8;      // frag chunk offset, ks=0
  const int co1 = ((1 * 4 + quad) ^ xq) * 8;      // frag chunk offset, ks=1

  float4v acc[2][4] = {};
  for (int kt = 0; kt < K; kt += 64) {
    gld16(Ab + (size_t)(w * 8 + lrow) * K + kt + lk_sw, &As[w * 8 * 64]);
#pragma unroll
    for (int j = 0; j < 8; j++) {
      const int r0 = w * 64 + j * 8;
      gld16(Bb + (size_t)(r0 + lrow) * K + kt + lk_sw, &Bs[r0 * 64]);
    }
    __syncthreads();
#pragma unroll
    for (int ks = 0; ks < 2; ks++) {
      const int co = ks ? co1 : co0;
      short8 af[2], bq[4];
#pragma unroll
      for (int mt = 0; mt < 2; mt++)
        af[mt] = *(const short8*)&As[(mt * 16 + l15) * 64 + co];
#pragma unroll
      for (int nt = 0; nt < 4; nt++)
        bq[nt] = *(const short8*)&Bs[(w * 64 + nt * 16 + l15) * 64 + co];
#pragma unroll
      for (int mt = 0; mt < 2; mt++)
#pragma unroll
        for (int nt = 0; nt < 4; nt++)
          acc[mt][nt] = __builtin_amdgcn_mfma_f32_16x16x32_bf16(af[mt], bq[nt], acc[mt][nt], 0, 0, 0);
    }
    __syncthreads();
  }
#pragma unroll
  for (int nt = 0; nt < 4; nt++) {
    const int col = n0 + w * 64 + nt * 16 + l15;
    const float bias = b1[e * FDIM + col];
#pragma unroll
    for (int mt = 0; mt < 2; mt++) {
      const int rbase = m0 + mt * 16 + quad * 4;
#pragma unroll
      for (int r = 0; r < 4; r++) {
        float v = acc[mt][nt][r] + bias;
        v = v > 0.f ? v : 0.f;
        h[((size_t)e * CAP + rbase + r) * FDIM + col] = f2bf(v);
      }
    }
  }
}

// ---------------- GEMM2: split-K partials pt[kc] = h @ W2 (chunk), bf16 out ----------------
// blockIdx.z = e * nsplit + kc; kshift = log2(nsplit)
__global__ __launch_bounds__(256) void gemm_ffn2(
    const unsigned short* __restrict__ h, const unsigned short* __restrict__ w2t,
    unsigned short* __restrict__ pt, const int* __restrict__ counts, int kshift)
{
  __shared__ __align__(16) unsigned short As[32 * 64];
  __shared__ __align__(16) unsigned short Bs[256 * 64];
  const int e = blockIdx.z >> kshift, kc = blockIdx.z & ((1 << kshift) - 1);
  int cnt = counts[e]; cnt = cnt < CAP ? cnt : CAP;
  const int m0 = blockIdx.y * 32;
  if (m0 >= cnt) return;
  const int n0 = blockIdx.x * 256;
  const int K = FDIM;
  const unsigned short* Ab = h + ((size_t)e * CAP + m0) * K;
  const unsigned short* Bb = w2t + ((size_t)e * DDIM + n0) * K;

  const int tid = threadIdx.x;
  const int w = tid >> 6, lane = tid & 63;
  const int lrow = lane >> 3;
  const int lk_sw = ((lane & 7) ^ lrow) * 8;
  const int l15 = lane & 15, quad = lane >> 4;
  const int xq = l15 & 7;
  const int co0 = ((0 * 4 + quad) ^ xq) * 8;
  const int co1 = ((1 * 4 + quad) ^ xq) * 8;

  float4v acc[2][4] = {};
  const int chunk = FDIM >> kshift;
  const int k_lo = kc * chunk, k_hi = k_lo + chunk;
  for (int kt = k_lo; kt < k_hi; kt += 64) {
    gld16(Ab + (size_t)(w * 8 + lrow) * K + kt + lk_sw, &As[w * 8 * 64]);
#pragma unroll
    for (int j = 0; j < 8; j++) {
      const int r0 = w * 64 + j * 8;
      gld16(Bb + (size_t)(r0 + lrow) * K + kt + lk_sw, &Bs[r0 * 64]);
    }
    __syncthreads();
#pragma unroll
    for (int ks = 0; ks < 2; ks++) {
      const int co = ks ? co1 : co0;
      short8 af[2], bq[4];
#pragma unroll
      for (int mt = 0; mt < 2; mt++)
        af[mt] = *(const short8*)&As[(mt * 16 + l15) * 64 + co];
#pragma unroll
      for (int nt = 0; nt < 4; nt++)
        bq[nt] = *(const short8*)&Bs[(w * 64 + nt * 16 + l15) * 64 + co];
#pragma unroll
      for (int mt = 0; mt < 2; mt++)
#pragma unroll
        for (int nt = 0; nt < 4; nt++)
          acc[mt][nt] = __builtin_amdgcn_mfma_f32_16x16x32_bf16(af[mt], bq[nt], acc[mt][nt], 0, 0, 0);
    }
    __syncthreads();
  }
  unsigned short* po = pt + (size_t)kc * (EXP * CAP) * DDIM + ((size_t)e * CAP) * DDIM;
#pragma unroll
  for (int mt = 0; mt < 2; mt++) {
#pragma unroll
    for (int r = 0; r < 4; r++) {
      const int row = m0 + mt * 16 + quad * 4 + r;
#pragma unroll
      for (int nt = 0; nt < 4; nt++)
        po[(size_t)row * DDIM + n0 + w * 64 + nt * 16 + l15] = f2bf(acc[mt][nt][r]);
    }
  }
}

// ---------------- combine: y[token] = (sum partials + b2) * gate, scatter fp32 ----------------
// also computes the two scalar losses (merged finalize)
__global__ __launch_bounds__(256) void combine_kernel(
    const unsigned short* __restrict__ pt, const float* __restrict__ b2,
    const int* __restrict__ tlist, const float* __restrict__ gslot,
    const int* __restrict__ counts, const float* __restrict__ sump,
    const float* __restrict__ zsum, float* __restrict__ y, int nsplit)
{
  if (blockIdx.x == 0 && threadIdx.x == 0) {
    float aux = 0.f;
#pragma unroll
    for (int e = 0; e < 8; e++) aux += (float)counts[e] * sump[e];
    float* outs = y + (size_t)T_TOK * DDIM;
    outs[0] = 8.f * aux / ((float)T_TOK * (float)T_TOK);
    outs[1] = zsum[0] * (1.f / (float)T_TOK);
  }
  const int wv = threadIdx.x >> 6, lane = threadIdx.x & 63;
  const int s = blockIdx.x * 4 + wv;
  const int e = s >> 10, c = s & (CAP - 1);
  int cnt = counts[e]; cnt = cnt < CAP ? cnt : CAP;
  if (c >= cnt) return;
  const int t = tlist[s];
  const float g = gslot[s];
  const float* br = b2 + e * DDIM;
  float* yr = y + (size_t)t * DDIM;
  const int c0 = lane * 16;
#pragma unroll
  for (int j = 0; j < 16; j += 4) {
    float a0 = br[c0 + j + 0], a1 = br[c0 + j + 1], a2 = br[c0 + j + 2], a3 = br[c0 + j + 3];
    const unsigned short* p = pt + (size_t)s * DDIM;
    for (int q = 0; q < nsplit; q++) {
      a0 += bf2f(p[c0 + j + 0]); a1 += bf2f(p[c0 + j + 1]);
      a2 += bf2f(p[c0 + j + 2]); a3 += bf2f(p[c0 + j + 3]);
      p += (size_t)(EXP * CAP) * DDIM;
    }
    float4 o; o.x = a0 * g; o.y = a1 * g; o.z = a2 * g; o.w = a3 * g;
    *(float4*)&yr[c0 + j] = o;
  }
}

extern "C" void kernel_launch(void* const* d_in, const int* in_sizes, int n_in,
                              void* d_out, int out_size, void* d_ws, size_t ws_size,
                              hipStream_t stream) {
  const float* x  = (const float*)d_in[0];
  const float* Wg = (const float*)d_in[1];
  const float* W1 = (const float*)d_in[2];
  const float* b1 = (const float*)d_in[3];
  const float* W2 = (const float*)d_in[4];
  const float* b2 = (const float*)d_in[5];
  float* out = (float*)d_out;
  char* ws = (char*)d_ws;

  int*            eidx  = (int*)(ws + O_EIDX);
  float*          gate  = (float*)(ws + O_GATE);
  int*            counts= (int*)(ws + O_COUNTS);
  float*          sump  = (float*)(ws + O_SUMP);
  float*          zsum  = (float*)(ws + O_ZSUM);
  int*            tlist = (int*)(ws + O_TLIST);
  float*          gslot = (float*)(ws + O_GSLOT);
  unsigned short* xb    = (unsigned short*)(ws + O_XB);
  unsigned short* wt    = (unsigned short*)(ws + O_WT);
  unsigned short* h     = (unsigned short*)(ws + O_H);
  unsigned short* pt    = (unsigned short*)(ws + O_PT);

  // split-K factor for gemm2: 4 if the workspace can hold 4 partial buffers
  const int kshift = (ws_size >= WS_NEED4) ? 2 : 1;
  const int nsplit = 1 << kshift;

  // zero y + scalar outputs, and the small accumulator region
  hipMemsetAsync(d_out, 0, (size_t)out_size * sizeof(float), stream);
  hipMemsetAsync(ws + O_COUNTS, 0, 256, stream);

  router_kernel<<<T_TOK / 4, 256, 0, stream>>>(x, Wg, eidx, gate, sump, zsum);
  scan_kernel<<<1, 512, 0, stream>>>(eidx, gate, tlist, gslot, counts);
  dispatch_kernel<<<(EXP * CAP) / 4, 256, 0, stream>>>(x, tlist, counts, xb);

  // W1 [E][1024][4096] -> wt [E][4096][1024] bf16
  transpose_cvt<<<dim3(FDIM / 64, DDIM / 64, EXP), 256, 0, stream>>>(W1, wt, DDIM, FDIM);
  gemm_ffn1<<<dim3(FDIM / 256, CAP / 32, EXP), 256, 0, stream>>>(xb, wt, b1, h, counts);

  // W2 [E][4096][1024] -> wt [E][1024][4096] bf16 (reuse buffer)
  transpose_cvt<<<dim3(DDIM / 64, FDIM / 64, EXP), 256, 0, stream>>>(W2, wt, FDIM, DDIM);
  // split-K over F: blockIdx.z = e*nsplit + kc
  gemm_ffn2<<<dim3(DDIM / 256, CAP / 32, EXP * nsplit), 256, 0, stream>>>(h, wt, pt, counts, kshift);
  combine_kernel<<<(EXP * CAP) / 4, 256, 0, stream>>>(pt, b2, tlist, gslot, counts, sump, zsum, out, nsplit);
}

// Round 6
// 515.386 us; speedup vs baseline: 1.0153x; 1.0153x over previous
//
#include <hip/hip_runtime.h>
#include <hip/hip_bf16.h>
#include <math.h>

// Problem constants (B=2,S=2048,D=1024,E=8,F=4096, capacity_factor=2.0)
#define T_TOK 4096
#define DDIM 1024
#define EXP 8
#define FDIM 4096
#define CAP 1024   // int(2.0 * 4096 / 8)

typedef __attribute__((ext_vector_type(8))) short short8;
typedef __attribute__((ext_vector_type(4))) float float4v;
typedef unsigned int u32;
typedef unsigned long long u64;

// ---- workspace layout (bytes) ----
#define O_EIDX   0            // int[4096]
#define O_GATE   (16<<10)     // float[4096]
#define O_COUNTS (32<<10)     // int[8]
#define O_SUMP   ((32<<10)+64)  // float[8]
#define O_ZSUM   ((32<<10)+128) // float[1]
#define O_TLIST  (40<<10)     // int[8*1024]
#define O_GSLOT  (72<<10)     // float[8*1024]
#define O_XB     (1<<20)      // bf16[8*1024*1024]   16 MiB
#define O_WT     (17<<20)     // bf16[8*4096*1024]   64 MiB (reused W1t then W2t)
#define O_H      (81<<20)     // bf16[8*1024*4096]   64 MiB
#define O_PT     (145<<20)    // bf16[nsplit][8*1024][1024] 32/64 MiB split-K partials
#define WS_NEED4 ((size_t)(145+64)<<20)

__device__ __forceinline__ unsigned short f2bf(float f) {
  __hip_bfloat16 b = __float2bfloat16(f);
  return *reinterpret_cast<unsigned short*>(&b);
}
__device__ __forceinline__ float bf2f(unsigned short u) {
  u32 x = ((u32)u) << 16;
  union { u32 u; float f; } c; c.u = x; return c.f;
}

__device__ __forceinline__ void gld16(const void* g, void* l) {
  __builtin_amdgcn_global_load_lds((const __attribute__((address_space(1))) u32*)g,
                                   (__attribute__((address_space(3))) u32*)l, 16, 0, 0);
}

// ---------------- router: logits (fp64 acc), softmax, argmax, loss partials ----------------
__global__ __launch_bounds__(256) void router_kernel(
    const float* __restrict__ x, const float* __restrict__ wg,
    int* __restrict__ eidx, float* __restrict__ gate,
    float* __restrict__ sum_probs, float* __restrict__ zsum)
{
  __shared__ float bp[9];
  const int tid = threadIdx.x;
  if (tid < 9) bp[tid] = 0.0f;
  __syncthreads();
  const int wv = tid >> 6, lane = tid & 63;
  const int t = blockIdx.x * 4 + wv;
  const float* xr = x + (size_t)t * DDIM;
  double acc[8] = {0,0,0,0,0,0,0,0};
#pragma unroll
  for (int j = 0; j < 4; j++) {
    const int d0 = j * 256 + lane * 4;
    const float4 xv = *(const float4*)&xr[d0];
    const float xd[4] = {xv.x, xv.y, xv.z, xv.w};
#pragma unroll
    for (int u = 0; u < 4; u++) {
      const float* wr = wg + (size_t)(d0 + u) * 8;
      const float4 w0 = *(const float4*)wr;
      const float4 w1 = *(const float4*)(wr + 4);
      const double xdd = (double)xd[u];
      acc[0] += xdd * (double)w0.x; acc[1] += xdd * (double)w0.y;
      acc[2] += xdd * (double)w0.z; acc[3] += xdd * (double)w0.w;
      acc[4] += xdd * (double)w1.x; acc[5] += xdd * (double)w1.y;
      acc[6] += xdd * (double)w1.z; acc[7] += xdd * (double)w1.w;
    }
  }
#pragma unroll
  for (int e = 0; e < 8; e++)
#pragma unroll
    for (int off = 32; off; off >>= 1)
      acc[e] += __shfl_xor(acc[e], off);
  if (lane == 0) {
    double m = acc[0]; int am = 0;
#pragma unroll
    for (int e = 1; e < 8; e++) if (acc[e] > m) { m = acc[e]; am = e; }
    float p[8]; float se = 0.f;
#pragma unroll
    for (int e = 0; e < 8; e++) { p[e] = __expf((float)(acc[e] - m)); se += p[e]; }
    const float inv = 1.f / se;
#pragma unroll
    for (int e = 0; e < 8; e++) atomicAdd(&bp[e], p[e] * inv);
    const float z = logf(se) + (float)m;
    atomicAdd(&bp[8], z * z);
    eidx[t] = am;
    gate[t] = p[am] * inv;
  }
  __syncthreads();
  if (tid < 8) atomicAdd(&sum_probs[tid], bp[tid]);
  if (tid == 8) atomicAdd(zsum, bp[8]);
}

// ---------------- scan: deterministic per-expert positions (token order) ----------------
__global__ __launch_bounds__(512) void scan_kernel(
    const int* __restrict__ eidx, const float* __restrict__ gate,
    int* __restrict__ tlist, float* __restrict__ gslot, int* __restrict__ counts)
{
  __shared__ int se[T_TOK];
  const int tid = threadIdx.x;
  for (int i = tid; i < T_TOK; i += 512) se[i] = eidx[i];
  __syncthreads();
  const int w = tid >> 6, lane = tid & 63;
  int base = 0;
  for (int ch = 0; ch < T_TOK / 64; ch++) {
    const int t = ch * 64 + lane;
    const int e = se[t];
    const u64 m = __ballot(e == w);
    if (e == w) {
      const int p = base + __popcll(m & ((1ull << lane) - 1ull));
      if (p < CAP) {
        tlist[w * CAP + p] = t;
        gslot[w * CAP + p] = gate[t];
      }
    }
    base += __popcll(m);
  }
  if (lane == 0) counts[w] = base;   // raw count (aux loss); cap applied at use
}

// ---------------- dispatch: gather kept tokens into compact bf16 buffer ----------------
__global__ __launch_bounds__(256) void dispatch_kernel(
    const float* __restrict__ x, const int* __restrict__ tlist,
    const int* __restrict__ counts, unsigned short* __restrict__ xb)
{
  const int wv = threadIdx.x >> 6, lane = threadIdx.x & 63;
  const int s = blockIdx.x * 4 + wv;           // slot id
  const int e = s >> 10, c = s & (CAP - 1);
  int cnt = counts[e]; cnt = cnt < CAP ? cnt : CAP;
  if (c >= cnt) return;
  const int t = tlist[s];
  const float* xr = x + (size_t)t * DDIM;
  unsigned short* orow = xb + (size_t)s * DDIM;
#pragma unroll
  for (int j = 0; j < 4; j++) {
    const int d0 = j * 256 + lane * 4;
    const float4 v = *(const float4*)&xr[d0];
    const u64 pk = (u64)f2bf(v.x) | ((u64)f2bf(v.y) << 16) |
                   ((u64)f2bf(v.z) << 32) | ((u64)f2bf(v.w) << 48);
    *(u64*)&orow[d0] = pk;
  }
}

// ---------------- transpose + fp32->bf16: [R][C] -> [C][R] per matrix ----------------
__global__ __launch_bounds__(256) void transpose_cvt(
    const float* __restrict__ src, unsigned short* __restrict__ dst, int R, int C)
{
  __shared__ float tile[64][65];
  const size_t mb = (size_t)blockIdx.z * (size_t)R * (size_t)C;
  const int r0 = blockIdx.y * 64, c0 = blockIdx.x * 64;
  const int t = threadIdx.x;
  const int lr = t >> 4, lc = (t & 15) * 4;
#pragma unroll
  for (int p = 0; p < 4; p++) {
    const float4 v = *(const float4*)&src[mb + (size_t)(r0 + p * 16 + lr) * C + c0 + lc];
    tile[p * 16 + lr][lc + 0] = v.x; tile[p * 16 + lr][lc + 1] = v.y;
    tile[p * 16 + lr][lc + 2] = v.z; tile[p * 16 + lr][lc + 3] = v.w;
  }
  __syncthreads();
  const int n = t >> 2;            // out row within tile (0..63)
  const int k0 = (t & 3) * 16;
  unsigned short o[16];
#pragma unroll
  for (int j = 0; j < 16; j++) o[j] = f2bf(tile[k0 + j][n]);
  unsigned short* d = &dst[mb + (size_t)(c0 + n) * R + r0 + k0];
  *(short8*)d = *(short8*)&o[0];
  *(short8*)(d + 8) = *(short8*)&o[8];
}

// ======================= GEMMs: 128x128, BK=64, XOR-swizzled LDS (m97 shape) ==============
// LDS store: chunk c (8 ushorts) of row r holds global k-chunk c ^ (r&7).
// Staging source offset per lane: ((lane&7) ^ (lane>>3)) * 8.
// Fragment read chunk: (ks*4 + quad) ^ (l15&7).
// 4 waves (2x2); wave w owns m[(w>>1)*64 ..+64) x n[(w&1)*64 ..+64): acc[4][4];
// 32 MFMA per barrier-pair per wave, 8 KB staged per wave per kt-iter = 256 B/MFMA.

// ---------------- GEMM1: h = relu(xb @ W1 + b1), bf16 out, 128x128 tile ----------------
__global__ __launch_bounds__(256) void gemm_ffn1(
    const unsigned short* __restrict__ xb, const unsigned short* __restrict__ w1t,
    const float* __restrict__ b1, unsigned short* __restrict__ h,
    const int* __restrict__ counts)
{
  __shared__ __align__(16) unsigned short As[128 * 64];
  __shared__ __align__(16) unsigned short Bs[128 * 64];
  const int e = blockIdx.z;
  int cnt = counts[e]; cnt = cnt < CAP ? cnt : CAP;
  const int m0 = blockIdx.y * 128;
  if (m0 >= cnt) return;
  const int n0 = blockIdx.x * 128;
  const int K = DDIM;
  const unsigned short* Ab = xb + ((size_t)e * CAP + m0) * K;
  const unsigned short* Bb = w1t + ((size_t)e * FDIM + n0) * K;

  const int tid = threadIdx.x;
  const int w = tid >> 6, lane = tid & 63;
  const int lrow = lane >> 3;
  const int lk_sw = ((lane & 7) ^ lrow) * 8;      // swizzled source k-offset
  const int wm = (w >> 1) * 64, wn = (w & 1) * 64;
  const int l15 = lane & 15, quad = lane >> 4;
  const int xq = l15 & 7;
  const int co0 = (quad ^ xq) * 8;                // frag chunk offset, ks=0
  const int co1 = ((4 + quad) ^ xq) * 8;          // frag chunk offset, ks=1

  float4v acc[4][4] = {};
  for (int kt = 0; kt < K; kt += 64) {
#pragma unroll
    for (int j = 0; j < 4; j++) {
      const int r0 = w * 32 + j * 8;
      gld16(Ab + (size_t)(r0 + lrow) * K + kt + lk_sw, &As[r0 * 64]);
      gld16(Bb + (size_t)(r0 + lrow) * K + kt + lk_sw, &Bs[r0 * 64]);
    }
    __syncthreads();
#pragma unroll
    for (int ks = 0; ks < 2; ks++) {
      const int co = ks ? co1 : co0;
      short8 af[4], bq[4];
#pragma unroll
      for (int mt = 0; mt < 4; mt++)
        af[mt] = *(const short8*)&As[(wm + mt * 16 + l15) * 64 + co];
#pragma unroll
      for (int nt = 0; nt < 4; nt++)
        bq[nt] = *(const short8*)&Bs[(wn + nt * 16 + l15) * 64 + co];
#pragma unroll
      for (int mt = 0; mt < 4; mt++)
#pragma unroll
        for (int nt = 0; nt < 4; nt++)
          acc[mt][nt] = __builtin_amdgcn_mfma_f32_16x16x32_bf16(af[mt], bq[nt], acc[mt][nt], 0, 0, 0);
    }
    __syncthreads();
  }
#pragma unroll
  for (int nt = 0; nt < 4; nt++) {
    const int col = n0 + wn + nt * 16 + l15;
    const float bias = b1[e * FDIM + col];
#pragma unroll
    for (int mt = 0; mt < 4; mt++) {
      const int rbase = m0 + wm + mt * 16 + quad * 4;
#pragma unroll
      for (int r = 0; r < 4; r++) {
        float v = acc[mt][nt][r] + bias;
        v = v > 0.f ? v : 0.f;
        h[((size_t)e * CAP + rbase + r) * FDIM + col] = f2bf(v);
      }
    }
  }
}

// ---------------- GEMM2: split-K partials pt[kc] = h @ W2 (chunk), bf16 out ----------------
// blockIdx.z = e * nsplit + kc; kshift = log2(nsplit)
__global__ __launch_bounds__(256) void gemm_ffn2(
    const unsigned short* __restrict__ h, const unsigned short* __restrict__ w2t,
    unsigned short* __restrict__ pt, const int* __restrict__ counts, int kshift)
{
  __shared__ __align__(16) unsigned short As[128 * 64];
  __shared__ __align__(16) unsigned short Bs[128 * 64];
  const int e = blockIdx.z >> kshift, kc = blockIdx.z & ((1 << kshift) - 1);
  int cnt = counts[e]; cnt = cnt < CAP ? cnt : CAP;
  const int m0 = blockIdx.y * 128;
  if (m0 >= cnt) return;
  const int n0 = blockIdx.x * 128;
  const int K = FDIM;
  const unsigned short* Ab = h + ((size_t)e * CAP + m0) * K;
  const unsigned short* Bb = w2t + ((size_t)e * DDIM + n0) * K;

  const int tid = threadIdx.x;
  const int w = tid >> 6, lane = tid & 63;
  const int lrow = lane >> 3;
  const int lk_sw = ((lane & 7) ^ lrow) * 8;
  const int wm = (w >> 1) * 64, wn = (w & 1) * 64;
  const int l15 = lane & 15, quad = lane >> 4;
  const int xq = l15 & 7;
  const int co0 = (quad ^ xq) * 8;
  const int co1 = ((4 + quad) ^ xq) * 8;

  float4v acc[4][4] = {};
  const int chunk = FDIM >> kshift;
  const int k_lo = kc * chunk, k_hi = k_lo + chunk;
  for (int kt = k_lo; kt < k_hi; kt += 64) {
#pragma unroll
    for (int j = 0; j < 4; j++) {
      const int r0 = w * 32 + j * 8;
      gld16(Ab + (size_t)(r0 + lrow) * K + kt + lk_sw, &As[r0 * 64]);
      gld16(Bb + (size_t)(r0 + lrow) * K + kt + lk_sw, &Bs[r0 * 64]);
    }
    __syncthreads();
#pragma unroll
    for (int ks = 0; ks < 2; ks++) {
      const int co = ks ? co1 : co0;
      short8 af[4], bq[4];
#pragma unroll
      for (int mt = 0; mt < 4; mt++)
        af[mt] = *(const short8*)&As[(wm + mt * 16 + l15) * 64 + co];
#pragma unroll
      for (int nt = 0; nt < 4; nt++)
        bq[nt] = *(const short8*)&Bs[(wn + nt * 16 + l15) * 64 + co];
#pragma unroll
      for (int mt = 0; mt < 4; mt++)
#pragma unroll
        for (int nt = 0; nt < 4; nt++)
          acc[mt][nt] = __builtin_amdgcn_mfma_f32_16x16x32_bf16(af[mt], bq[nt], acc[mt][nt], 0, 0, 0);
    }
    __syncthreads();
  }
  unsigned short* po = pt + (size_t)kc * (EXP * CAP) * DDIM + ((size_t)e * CAP) * DDIM;
#pragma unroll
  for (int mt = 0; mt < 4; mt++) {
#pragma unroll
    for (int r = 0; r < 4; r++) {
      const int row = m0 + wm + mt * 16 + quad * 4 + r;
#pragma unroll
      for (int nt = 0; nt < 4; nt++)
        po[(size_t)row * DDIM + n0 + wn + nt * 16 + l15] = f2bf(acc[mt][nt][r]);
    }
  }
}

// ---------------- combine: y[token] = (sum partials + b2) * gate, scatter fp32 ----------------
// also computes the two scalar losses (merged finalize)
__global__ __launch_bounds__(256) void combine_kernel(
    const unsigned short* __restrict__ pt, const float* __restrict__ b2,
    const int* __restrict__ tlist, const float* __restrict__ gslot,
    const int* __restrict__ counts, const float* __restrict__ sump,
    const float* __restrict__ zsum, float* __restrict__ y, int nsplit)
{
  if (blockIdx.x == 0 && threadIdx.x == 0) {
    float aux = 0.f;
#pragma unroll
    for (int e = 0; e < 8; e++) aux += (float)counts[e] * sump[e];
    float* outs = y + (size_t)T_TOK * DDIM;
    outs[0] = 8.f * aux / ((float)T_TOK * (float)T_TOK);
    outs[1] = zsum[0] * (1.f / (float)T_TOK);
  }
  const int wv = threadIdx.x >> 6, lane = threadIdx.x & 63;
  const int s = blockIdx.x * 4 + wv;
  const int e = s >> 10, c = s & (CAP - 1);
  int cnt = counts[e]; cnt = cnt < CAP ? cnt : CAP;
  if (c >= cnt) return;
  const int t = tlist[s];
  const float g = gslot[s];
  const float* br = b2 + e * DDIM;
  float* yr = y + (size_t)t * DDIM;
  const int c0 = lane * 16;
#pragma unroll
  for (int j = 0; j < 16; j += 4) {
    float a0 = br[c0 + j + 0], a1 = br[c0 + j + 1], a2 = br[c0 + j + 2], a3 = br[c0 + j + 3];
    const unsigned short* p = pt + (size_t)s * DDIM;
    for (int q = 0; q < nsplit; q++) {
      a0 += bf2f(p[c0 + j + 0]); a1 += bf2f(p[c0 + j + 1]);
      a2 += bf2f(p[c0 + j + 2]); a3 += bf2f(p[c0 + j + 3]);
      p += (size_t)(EXP * CAP) * DDIM;
    }
    float4 o; o.x = a0 * g; o.y = a1 * g; o.z = a2 * g; o.w = a3 * g;
    *(float4*)&yr[c0 + j] = o;
  }
}

extern "C" void kernel_launch(void* const* d_in, const int* in_sizes, int n_in,
                              void* d_out, int out_size, void* d_ws, size_t ws_size,
                              hipStream_t stream) {
  const float* x  = (const float*)d_in[0];
  const float* Wg = (const float*)d_in[1];
  const float* W1 = (const float*)d_in[2];
  const float* b1 = (const float*)d_in[3];
  const float* W2 = (const float*)d_in[4];
  const float* b2 = (const float*)d_in[5];
  float* out = (float*)d_out;
  char* ws = (char*)d_ws;

  int*            eidx  = (int*)(ws + O_EIDX);
  float*          gate  = (float*)(ws + O_GATE);
  int*            counts= (int*)(ws + O_COUNTS);
  float*          sump  = (float*)(ws + O_SUMP);
  float*          zsum  = (float*)(ws + O_ZSUM);
  int*            tlist = (int*)(ws + O_TLIST);
  float*          gslot = (float*)(ws + O_GSLOT);
  unsigned short* xb    = (unsigned short*)(ws + O_XB);
  unsigned short* wt    = (unsigned short*)(ws + O_WT);
  unsigned short* h     = (unsigned short*)(ws + O_H);
  unsigned short* pt    = (unsigned short*)(ws + O_PT);

  // split-K factor for gemm2: 4 if the workspace can hold 4 partial buffers
  const int kshift = (ws_size >= WS_NEED4) ? 2 : 1;
  const int nsplit = 1 << kshift;

  // zero y + scalar outputs, and the small accumulator region
  hipMemsetAsync(d_out, 0, (size_t)out_size * sizeof(float), stream);
  hipMemsetAsync(ws + O_COUNTS, 0, 256, stream);

  router_kernel<<<T_TOK / 4, 256, 0, stream>>>(x, Wg, eidx, gate, sump, zsum);
  scan_kernel<<<1, 512, 0, stream>>>(eidx, gate, tlist, gslot, counts);
  dispatch_kernel<<<(EXP * CAP) / 4, 256, 0, stream>>>(x, tlist, counts, xb);

  // W1 [E][1024][4096] -> wt [E][4096][1024] bf16
  transpose_cvt<<<dim3(FDIM / 64, DDIM / 64, EXP), 256, 0, stream>>>(W1, wt, DDIM, FDIM);
  gemm_ffn1<<<dim3(FDIM / 128, CAP / 128, EXP), 256, 0, stream>>>(xb, wt, b1, h, counts);

  // W2 [E][4096][1024] -> wt [E][1024][4096] bf16 (reuse buffer)
  transpose_cvt<<<dim3(DDIM / 64, FDIM / 64, EXP), 256, 0, stream>>>(W2, wt, FDIM, DDIM);
  // split-K over F: blockIdx.z = e*nsplit + kc
  gemm_ffn2<<<dim3(DDIM / 128, CAP / 128, EXP * nsplit), 256, 0, stream>>>(h, wt, pt, counts, kshift);
  combine_kernel<<<(EXP * CAP) / 4, 256, 0, stream>>>(pt, b2, tlist, gslot, counts, sump, zsum, out, nsplit);
}